// Round 6
// baseline (179.801 us; speedup 1.0000x reference)
//
#include <hip/hip_runtime.h>

#define B 8
#define NG 2                   // batch groups
#define GB 4                   // batches per group
#define CCH 3
#define HH 512
#define WW 512
#define WIN 21
#define PAD 10
#define TSX 32
#define TSY 32
#define PTY 52                 // TSY + 2*PAD rows staged
#define TROW 60                // tile row stride (dwords)
#define HSH 53                 // hs rows per column (odd -> max 2-way on hsum write)
#define NSLOT 676              // 52 rows x 13 float4 groups
#define NPIX (CCH * HH * WW)

// Kernel 1: one block = (tile, channel, batch-group of 4). Accumulates this
// group's (sum w*p, sum w) into its private float2 workspace slice.
__global__ __launch_bounds__(256, 6) void nlm_accum_kernel(const float* __restrict__ noisy,
                                                           float2* __restrict__ ws) {
    __shared__ float  tile[PTY][TROW];     // 12480 B
    __shared__ float2 hs_t[TSX][HSH];      // 13568 B

    const int tid = threadIdx.x;
    const int x0 = blockIdx.x * TSX;
    const int y0 = blockIdx.y * TSY;
    const int ch = blockIdx.z % CCH;
    const int g  = blockIdx.z / CCH;

    // ---- precompute staging slots (batch-invariant addresses) ----
    int   rowbase[3], gxs[3];
    float* ldsp[3];
    bool  valid[3], edge[3];
    #pragma unroll
    for (int k = 0; k < 3; ++k) {
        int s = tid + 256 * k;
        valid[k] = (s < NSLOT);
        int ss = valid[k] ? s : 0;
        int r  = ss / 13;
        int c4 = ss - r * 13;
        int gy = y0 + r - PAD;
        gy = (gy < 0) ? -gy : ((gy >= HH) ? (2 * (HH - 1) - gy) : gy);
        int gx = x0 + (c4 << 2) - PAD;
        rowbase[k] = gy * WW;
        gxs[k]     = gx;
        edge[k]    = (gx < 0) || (gx > WW - 4);
        ldsp[k]    = &tile[r][c4 << 2];
    }

    const float* src0 = noisy + (size_t)(g * GB * CCH + ch) * (HH * WW);
    float4 pre[3];
    #pragma unroll
    for (int k = 0; k < 3; ++k) {
        if (valid[k]) {
            if (!edge[k]) {
                pre[k] = *(const float4*)(src0 + rowbase[k] + gxs[k]);
            } else {
                float tmp[4];
                #pragma unroll
                for (int t = 0; t < 4; ++t) {
                    int gx = gxs[k] + t;
                    gx = (gx < 0) ? -gx : ((gx >= WW) ? (2 * (WW - 1) - gx) : gx);
                    tmp[t] = src0[rowbase[k] + gx];
                }
                pre[k] = make_float4(tmp[0], tmp[1], tmp[2], tmp[3]);
            }
        }
    }

    float num[4] = {0.f, 0.f, 0.f, 0.f};
    float den[4] = {0.f, 0.f, 0.f, 0.f};

    const int tx  = tid & 31;
    const int ty0 = (tid >> 5) << 2;       // 4 consecutive output rows / thread

    for (int lb = 0; lb < GB; ++lb) {
        __syncthreads();                   // previous tile fully consumed
        #pragma unroll
        for (int k = 0; k < 3; ++k)
            if (valid[k]) *(float4*)ldsp[k] = pre[k];
        __syncthreads();

        // prefetch next batch in group; latency hides behind compute
        if (lb < GB - 1) {
            const float* srcn = noisy + (size_t)((g * GB + lb + 1) * CCH + ch) * (HH * WW);
            #pragma unroll
            for (int k = 0; k < 3; ++k) {
                if (valid[k]) {
                    if (!edge[k]) {
                        pre[k] = *(const float4*)(srcn + rowbase[k] + gxs[k]);
                    } else {
                        float tmp[4];
                        #pragma unroll
                        for (int t = 0; t < 4; ++t) {
                            int gx = gxs[k] + t;
                            gx = (gx < 0) ? -gx : ((gx >= WW) ? (2 * (WW - 1) - gx) : gx);
                            tmp[t] = srcn[rowbase[k] + gx];
                        }
                        pre[k] = make_float4(tmp[0], tmp[1], tmp[2], tmp[3]);
                    }
                }
            }
        }

        // ---- horizontal box sums: 52 rows x 4 segments of 8 output cols ----
        if (tid < PTY * 4) {
            int r   = tid >> 2;
            int cx0 = (tid & 3) << 3;      // 0,8,16,24
            float v[28];
            #pragma unroll
            for (int q = 0; q < 7; ++q)
                *(float4*)&v[q * 4] = *(const float4*)&tile[r][cx0 + (q << 2)];
            float s1 = 0.f, s2 = 0.f;
            #pragma unroll
            for (int k = 0; k <= 20; ++k) { s1 += v[k]; s2 = fmaf(v[k], v[k], s2); }
            hs_t[cx0][r] = make_float2(s1, s2);
            #pragma unroll
            for (int j = 1; j < 8; ++j) {
                float vo = v[j - 1], vn = v[j + 20];
                s1 += vn - vo;
                s2 += vn * vn - vo * vo;
                hs_t[cx0 + j][r] = make_float2(s1, s2);
            }
        }
        __syncthreads();

        // ---- vertical sliding sums: 4 output rows per thread ----
        float2 h0 = hs_t[tx][ty0];
        float2 h1 = hs_t[tx][ty0 + 1];
        float2 h2 = hs_t[tx][ty0 + 2];
        float vs1 = h0.x + h1.x + h2.x;
        float vs2 = h0.y + h1.y + h2.y;
        #pragma unroll
        for (int k = 3; k <= 20; ++k) {
            float2 h = hs_t[tx][ty0 + k];
            vs1 += h.x;
            vs2 += h.y;
        }
        const float kE = (-100.0f / 441.0f) * 1.44269504088896f;  // fold 1/h^2, 1/n, 1/ln2
        {
            float a = tile[ty0 + PAD][tx + PAD];
            float p = tile[ty0][tx];
            float dd = fmaf(a, fmaf(441.f, a, -2.f * vs1), vs2);
            float w = exp2f(dd * kE);
            num[0] += w * p; den[0] += w;
        }
        #pragma unroll
        for (int i = 1; i < 4; ++i) {
            float2 hn = hs_t[tx][ty0 + 20 + i];
            float2 ho = (i == 1) ? h0 : ((i == 2) ? h1 : h2);
            vs1 += hn.x - ho.x;
            vs2 += hn.y - ho.y;
            float a = tile[ty0 + i + PAD][tx + PAD];
            float p = tile[ty0 + i][tx];
            float dd = fmaf(a, fmaf(441.f, a, -2.f * vs1), vs2);
            float w = exp2f(dd * kE);
            num[i] += w * p; den[i] += w;
        }
    }

    // ---- store group partials (coalesced b64, no atomics) ----
    float2* wsg = ws + (size_t)g * NPIX;
    #pragma unroll
    for (int i = 0; i < 4; ++i) {
        int y = y0 + ty0 + i;
        int x = x0 + tx;
        wsg[((size_t)ch * HH + y) * WW + x] = make_float2(num[i], den[i]);
    }
}

// Kernel 2: combine 2 group partials, normalize, broadcast to 8 batch slices.
// 4 pixels per thread, all float4 traffic.
__global__ __launch_bounds__(256) void nlm_finalize_kernel(const float* __restrict__ ws,
                                                           float* __restrict__ out) {
    int i4 = (blockIdx.x * 256 + threadIdx.x) << 2;   // first of 4 pixels
    const float* g0 = ws + ((size_t)i4 << 1);
    const float* g1 = g0 + ((size_t)NPIX << 1);
    float4 a0 = *(const float4*)g0;        // pixels i4, i4+1 (n,d,n,d)
    float4 a1 = *(const float4*)(g0 + 4);  // pixels i4+2, i4+3
    float4 b0 = *(const float4*)g1;
    float4 b1 = *(const float4*)(g1 + 4);
    float4 v;
    v.x = (a0.x + b0.x) / (a0.y + b0.y + 1e-10f);
    v.y = (a0.z + b0.z) / (a0.w + b0.w + 1e-10f);
    v.z = (a1.x + b1.x) / (a1.y + b1.y + 1e-10f);
    v.w = (a1.z + b1.z) / (a1.w + b1.w + 1e-10f);
    v.x = v.x < 0.f ? 0.f : (v.x > 1.f ? 1.f : v.x);
    v.y = v.y < 0.f ? 0.f : (v.y > 1.f ? 1.f : v.y);
    v.z = v.z < 0.f ? 0.f : (v.z > 1.f ? 1.f : v.z);
    v.w = v.w < 0.f ? 0.f : (v.w > 1.f ? 1.f : v.w);
    #pragma unroll
    for (int b = 0; b < B; ++b)
        *(float4*)(out + (size_t)b * NPIX + i4) = v;
}

extern "C" void kernel_launch(void* const* d_in, const int* in_sizes, int n_in,
                              void* d_out, int out_size, void* d_ws, size_t ws_size,
                              hipStream_t stream) {
    const float* noisy = (const float*)d_in[0];
    float* out = (float*)d_out;
    float2* ws = (float2*)d_ws;

    dim3 grid1(WW / TSX, HH / TSY, CCH * NG);
    nlm_accum_kernel<<<grid1, dim3(256), 0, stream>>>(noisy, ws);

    dim3 grid2(NPIX / (256 * 4));
    nlm_finalize_kernel<<<grid2, dim3(256), 0, stream>>>((const float*)d_ws, out);
}

// Round 7
// 93.204 us; speedup vs baseline: 1.9291x; 1.9291x over previous
//
#include <hip/hip_runtime.h>

#define B 8
#define CCH 3
#define HH 512
#define WW 512
#define WIN 21
#define PAD 10
#define TSX 32
#define TSY 32
#define PTY 52                 // TSY + 2*PAD rows staged
#define TROW 60                // tile row stride (dwords); 16B-aligned rows
#define HSH 53                 // hs rows per column (odd stride -> 2-way max, free)
#define NSLOT 676              // 52 rows x 13 float4 groups
#define NT 512                 // threads per block (8 waves)

__global__ __launch_bounds__(NT, 6) void nlm_fused_kernel(const float* __restrict__ noisy,
                                                          float* __restrict__ out) {
    __shared__ float  tile[PTY][TROW];     // 12480 B
    __shared__ float2 hs_t[TSX][HSH];      // [col][row] (s1,s2), 13568 B

    const int tid = threadIdx.x;
    const int x0 = blockIdx.x * TSX;
    const int y0 = blockIdx.y * TSY;
    const int ch = blockIdx.z;

    // ---- precompute staging slots (batch-invariant addresses) ----
    int   rowbase[2], gxs[2];
    float* ldsp[2];
    bool  valid[2], edge[2];
    #pragma unroll
    for (int k = 0; k < 2; ++k) {
        int s = tid + NT * k;
        valid[k] = (s < NSLOT);
        int ss = valid[k] ? s : 0;
        int r  = ss / 13;
        int c4 = ss - r * 13;
        int gy = y0 + r - PAD;
        gy = (gy < 0) ? -gy : ((gy >= HH) ? (2 * (HH - 1) - gy) : gy);
        int gx = x0 + (c4 << 2) - PAD;
        rowbase[k] = gy * WW;
        gxs[k]     = gx;
        edge[k]    = (gx < 0) || (gx > WW - 4);
        ldsp[k]    = &tile[r][c4 << 2];
    }

    const float* src0 = noisy + (size_t)ch * (HH * WW);
    float4 pre[2];
    #pragma unroll
    for (int k = 0; k < 2; ++k) {
        if (valid[k]) {
            if (!edge[k]) {
                pre[k] = *(const float4*)(src0 + rowbase[k] + gxs[k]);
            } else {
                float tmp[4];
                #pragma unroll
                for (int t = 0; t < 4; ++t) {
                    int gx = gxs[k] + t;
                    gx = (gx < 0) ? -gx : ((gx >= WW) ? (2 * (WW - 1) - gx) : gx);
                    tmp[t] = src0[rowbase[k] + gx];
                }
                pre[k] = make_float4(tmp[0], tmp[1], tmp[2], tmp[3]);
            }
        }
    }

    float num[2] = {0.f, 0.f};
    float den[2] = {0.f, 0.f};

    const int tx  = tid & 31;
    const int ty0 = (tid >> 5) << 1;       // 2 consecutive output rows / thread (even)

    for (int b = 0; b < B; ++b) {
        __syncthreads();                   // previous tile fully consumed
        #pragma unroll
        for (int k = 0; k < 2; ++k)
            if (valid[k]) *(float4*)ldsp[k] = pre[k];
        __syncthreads();

        // prefetch next batch; HBM latency hides behind hsum+vertical
        if (b < B - 1) {
            const float* srcn = noisy + (size_t)((b + 1) * CCH + ch) * (HH * WW);
            #pragma unroll
            for (int k = 0; k < 2; ++k) {
                if (valid[k]) {
                    if (!edge[k]) {
                        pre[k] = *(const float4*)(srcn + rowbase[k] + gxs[k]);
                    } else {
                        float tmp[4];
                        #pragma unroll
                        for (int t = 0; t < 4; ++t) {
                            int gx = gxs[k] + t;
                            gx = (gx < 0) ? -gx : ((gx >= WW) ? (2 * (WW - 1) - gx) : gx);
                            tmp[t] = srcn[rowbase[k] + gx];
                        }
                        pre[k] = make_float4(tmp[0], tmp[1], tmp[2], tmp[3]);
                    }
                }
            }
        }

        // ---- horizontal box sums: 52 rows x 8 segments of 4 output cols ----
        // reads 24 floats (6 x b128, conflict-free), emits 4 (s1,s2) pairs
        if (tid < PTY * 8) {
            int r   = tid >> 3;
            int cx0 = (tid & 7) << 2;      // 0,4,...,28
            float v[24];
            #pragma unroll
            for (int q = 0; q < 6; ++q)
                *(float4*)&v[q * 4] = *(const float4*)&tile[r][cx0 + (q << 2)];
            float s1 = 0.f, s2 = 0.f;
            #pragma unroll
            for (int k = 0; k <= 20; ++k) { s1 += v[k]; s2 = fmaf(v[k], v[k], s2); }
            hs_t[cx0][r] = make_float2(s1, s2);
            #pragma unroll
            for (int j = 1; j < 4; ++j) {
                float vo = v[j - 1], vn = v[j + 20];
                s1 += vn - vo;
                s2 += vn * vn - vo * vo;
                hs_t[cx0 + j][r] = make_float2(s1, s2);
            }
        }
        __syncthreads();

        // ---- vertical sliding sums: 2 output rows per thread ----
        float2 h0 = hs_t[tx][ty0];
        float vs1 = h0.x, vs2 = h0.y;
        #pragma unroll
        for (int k = 1; k <= 20; ++k) {
            float2 h = hs_t[tx][ty0 + k];
            vs1 += h.x;
            vs2 += h.y;
        }
        const float kE = (-100.0f / 441.0f) * 1.44269504088896f;  // 1/h^2 * 1/n * 1/ln2
        {
            float a = tile[ty0 + PAD][tx + PAD];
            float p = tile[ty0][tx];
            float dd = fmaf(a, fmaf(441.f, a, -2.f * vs1), vs2);
            float w = exp2f(dd * kE);
            num[0] += w * p; den[0] += w;
        }
        {
            float2 h21 = hs_t[tx][ty0 + 21];
            vs1 += h21.x - h0.x;
            vs2 += h21.y - h0.y;
            float a = tile[ty0 + 1 + PAD][tx + PAD];
            float p = tile[ty0 + 1][tx];
            float dd = fmaf(a, fmaf(441.f, a, -2.f * vs1), vs2);
            float w = exp2f(dd * kE);
            num[1] += w * p; den[1] += w;
        }
    }

    // ---- epilogue: identical value for all 8 batch slices ----
    #pragma unroll
    for (int i = 0; i < 2; ++i) {
        int y = y0 + ty0 + i;
        int x = x0 + tx;
        float v = num[i] / (den[i] + 1e-10f);
        v = v < 0.f ? 0.f : (v > 1.f ? 1.f : v);
        #pragma unroll
        for (int b = 0; b < B; ++b)
            out[((size_t)(b * CCH + ch) * HH + y) * WW + x] = v;
    }
}

extern "C" void kernel_launch(void* const* d_in, const int* in_sizes, int n_in,
                              void* d_out, int out_size, void* d_ws, size_t ws_size,
                              hipStream_t stream) {
    const float* noisy = (const float*)d_in[0];
    float* out = (float*)d_out;
    dim3 grid(WW / TSX, HH / TSY, CCH);
    nlm_fused_kernel<<<grid, dim3(NT), 0, stream>>>(noisy, out);
}

// Round 8
// 90.552 us; speedup vs baseline: 1.9856x; 1.0293x over previous
//
#include <hip/hip_runtime.h>

#define B 8
#define CCH 3
#define HH 512
#define WW 512
#define WIN 21
#define PAD 10
#define TSX 32
#define TSY 32
#define PTY 52                 // TSY + 2*PAD rows staged
#define TROW 60                // tile row stride (dwords); 16B-aligned, bank-sweeping
#define HSH 53                 // hs rows per column (odd stride -> 2-way max, free)
#define NSLOT 676              // 52 rows x 13 float4 groups

// Phase schedule (2 barriers/batch, double-buffered LDS):
//   pre = load(b0); write T[0]; pre = load(b1); barrier
//   for b in 0..7:
//     hsum_b   : T[b&1] -> H[b&1]
//     barrier X_b
//     stage    : T[(b+1)&1] <- pre        (b<7)
//     prefetch : pre <- batch b+2         (b<6)   [issued before vert -> drain covered]
//     vert_b   : H[b&1], T[b&1] -> num/den
//     barrier Y_b                          (b<7)
// Races checked: stage_{b+1} writes T[(b+1)&1] while vert_b reads T[b&1] (different);
// prior readers of T[(b+1)&1] (hsum_{b-1}, vert_{b-1}) end before Y_{b-1} < stage_{b+1}.
// H[b&1] prior reader vert_{b-2} ends 2 barriers earlier.
__global__ __launch_bounds__(256, 3) void nlm_fused_kernel(const float* __restrict__ noisy,
                                                           float* __restrict__ out) {
    __shared__ float  tile[2][PTY][TROW];   // 2 x 12480 B
    __shared__ float2 hs_t[2][TSX][HSH];    // 2 x 13568 B   (total 52096 B)

    const int tid = threadIdx.x;
    const int x0 = blockIdx.x * TSX;
    const int y0 = blockIdx.y * TSY;
    const int ch = blockIdx.z;

    // ---- precompute staging slots (batch-invariant) ----
    int   rowbase[3], gxs[3], lr[3], lc[3];
    bool  valid[3], edge[3];
    #pragma unroll
    for (int k = 0; k < 3; ++k) {
        int s = tid + 256 * k;
        valid[k] = (s < NSLOT);
        int ss = valid[k] ? s : 0;
        int r  = ss / 13;
        int c4 = ss - r * 13;
        int gy = y0 + r - PAD;
        gy = (gy < 0) ? -gy : ((gy >= HH) ? (2 * (HH - 1) - gy) : gy);
        int gx = x0 + (c4 << 2) - PAD;
        rowbase[k] = gy * WW;
        gxs[k]     = gx;
        edge[k]    = (gx < 0) || (gx > WW - 4);
        lr[k]      = r;
        lc[k]      = c4 << 2;
    }

    float4 pre[3];
    auto prefetch = [&](int bb) {
        const float* src = noisy + (size_t)(bb * CCH + ch) * (HH * WW);
        #pragma unroll
        for (int k = 0; k < 3; ++k) {
            if (valid[k]) {
                if (!edge[k]) {
                    pre[k] = *(const float4*)(src + rowbase[k] + gxs[k]);
                } else {
                    float tmp[4];
                    #pragma unroll
                    for (int t = 0; t < 4; ++t) {
                        int gx = gxs[k] + t;
                        gx = (gx < 0) ? -gx : ((gx >= WW) ? (2 * (WW - 1) - gx) : gx);
                        tmp[t] = src[rowbase[k] + gx];
                    }
                    pre[k] = make_float4(tmp[0], tmp[1], tmp[2], tmp[3]);
                }
            }
        }
    };

    prefetch(0);
    #pragma unroll
    for (int k = 0; k < 3; ++k)
        if (valid[k]) *(float4*)&tile[0][lr[k]][lc[k]] = pre[k];
    prefetch(1);
    __syncthreads();

    float num[4] = {0.f, 0.f, 0.f, 0.f};
    float den[4] = {0.f, 0.f, 0.f, 0.f};

    const int tx  = tid & 31;
    const int ty0 = (tid >> 5) << 2;        // 4 consecutive output rows / thread
    const int hr  = tid >> 2;               // hsum row (0..63; valid < 52)
    const int hc0 = (tid & 3) << 3;         // hsum first col: 0,8,16,24

    for (int b = 0; b < B; ++b) {
        const int cur = b & 1;
        // ---- phase 1: horizontal box sums for batch b ----
        if (hr < PTY) {
            float v[28];
            #pragma unroll
            for (int q = 0; q < 7; ++q)
                *(float4*)&v[q * 4] = *(const float4*)&tile[cur][hr][hc0 + (q << 2)];
            float s1 = 0.f, s2 = 0.f;
            #pragma unroll
            for (int k = 0; k <= 20; ++k) { s1 += v[k]; s2 = fmaf(v[k], v[k], s2); }
            hs_t[cur][hc0][hr] = make_float2(s1, s2);
            #pragma unroll
            for (int j = 1; j < 8; ++j) {
                float vo = v[j - 1], vn = v[j + 20];
                s1 += vn - vo;
                s2 += vn * vn - vo * vo;
                hs_t[cur][hc0 + j][hr] = make_float2(s1, s2);
            }
        }
        __syncthreads();                    // X_b

        // ---- phase 2: stage b+1, issue prefetch b+2, vertical for b ----
        if (b < B - 1) {
            #pragma unroll
            for (int k = 0; k < 3; ++k)
                if (valid[k]) *(float4*)&tile[1 - cur][lr[k]][lc[k]] = pre[k];
            if (b < B - 2) prefetch(b + 2);   // drain covered by vert below
        }

        float2 h0 = hs_t[cur][tx][ty0];
        float2 h1 = hs_t[cur][tx][ty0 + 1];
        float2 h2 = hs_t[cur][tx][ty0 + 2];
        float vs1 = h0.x + h1.x + h2.x;
        float vs2 = h0.y + h1.y + h2.y;
        #pragma unroll
        for (int k = 3; k <= 20; ++k) {
            float2 h = hs_t[cur][tx][ty0 + k];
            vs1 += h.x;
            vs2 += h.y;
        }
        const float kE = (-100.0f / 441.0f) * 1.44269504088896f;  // 1/h^2 * 1/n * 1/ln2
        {
            float a = tile[cur][ty0 + PAD][tx + PAD];
            float p = tile[cur][ty0][tx];
            float dd = fmaf(a, fmaf(441.f, a, -2.f * vs1), vs2);
            float w = exp2f(dd * kE);
            num[0] += w * p; den[0] += w;
        }
        #pragma unroll
        for (int i = 1; i < 4; ++i) {
            float2 hn = hs_t[cur][tx][ty0 + 20 + i];
            float2 ho = (i == 1) ? h0 : ((i == 2) ? h1 : h2);
            vs1 += hn.x - ho.x;
            vs2 += hn.y - ho.y;
            float a = tile[cur][ty0 + i + PAD][tx + PAD];
            float p = tile[cur][ty0 + i][tx];
            float dd = fmaf(a, fmaf(441.f, a, -2.f * vs1), vs2);
            float w = exp2f(dd * kE);
            num[i] += w * p; den[i] += w;
        }
        if (b < B - 1) __syncthreads();     // Y_b
    }

    // ---- epilogue: identical value for all 8 batch slices ----
    #pragma unroll
    for (int i = 0; i < 4; ++i) {
        int y = y0 + ty0 + i;
        int x = x0 + tx;
        float v = num[i] / (den[i] + 1e-10f);
        v = v < 0.f ? 0.f : (v > 1.f ? 1.f : v);
        #pragma unroll
        for (int b = 0; b < B; ++b)
            out[((size_t)(b * CCH + ch) * HH + y) * WW + x] = v;
    }
}

extern "C" void kernel_launch(void* const* d_in, const int* in_sizes, int n_in,
                              void* d_out, int out_size, void* d_ws, size_t ws_size,
                              hipStream_t stream) {
    const float* noisy = (const float*)d_in[0];
    float* out = (float*)d_out;
    dim3 grid(WW / TSX, HH / TSY, CCH);
    nlm_fused_kernel<<<grid, dim3(256), 0, stream>>>(noisy, out);
}

// Round 9
// 90.024 us; speedup vs baseline: 1.9973x; 1.0059x over previous
//
#include <hip/hip_runtime.h>

#define B 8
#define CCH 3
#define HH 512
#define WW 512
#define PAD 10
#define TSX 32
#define TSY 32
#define PTY 52                 // TSY + 2*PAD rows staged
#define TROW 60                // tile row stride (dwords); 16B-aligned
#define HSH 53                 // hs rows per column
#define NSLOT 676              // 52 rows x 13 float4 groups
#define NT 128                 // 2 waves
#define NPRE 6                 // ceil(676/128) staging slots per thread

__global__ __launch_bounds__(NT) void nlm_fused_kernel(const float* __restrict__ noisy,
                                                       float* __restrict__ out) {
    __shared__ float  tile[PTY][TROW];     // 12480 B  (read only by hsum)
    __shared__ float2 hs_t[TSX][HSH];      // 13568 B  (read only by vert)

    const int tid = threadIdx.x;
    const int x0 = blockIdx.x * TSX;
    const int y0 = blockIdx.y * TSY;
    const int ch = blockIdx.z;

    // ---- staging slots (batch-invariant addresses), 6 per thread ----
    int   rowbase[NPRE], gxs[NPRE];
    float* ldsp[NPRE];
    bool  valid[NPRE], edge[NPRE];
    #pragma unroll
    for (int k = 0; k < NPRE; ++k) {
        int s = tid + NT * k;
        valid[k] = (s < NSLOT);
        int ss = valid[k] ? s : 0;
        int r  = ss / 13;
        int c4 = ss - r * 13;
        int gy = y0 + r - PAD;
        gy = (gy < 0) ? -gy : ((gy >= HH) ? (2 * (HH - 1) - gy) : gy);
        int gx = x0 + (c4 << 2) - PAD;
        rowbase[k] = gy * WW;
        gxs[k]     = gx;
        edge[k]    = (gx < 0) || (gx > WW - 4);
        ldsp[k]    = &tile[r][c4 << 2];
    }

    float4 pre[NPRE];
    auto prefetch = [&](int bb) {
        const float* src = noisy + (size_t)(bb * CCH + ch) * (HH * WW);
        #pragma unroll
        for (int k = 0; k < NPRE; ++k) {
            if (valid[k]) {
                if (!edge[k]) {
                    pre[k] = *(const float4*)(src + rowbase[k] + gxs[k]);
                } else {
                    float tmp[4];
                    #pragma unroll
                    for (int t = 0; t < 4; ++t) {
                        int gx = gxs[k] + t;
                        gx = (gx < 0) ? -gx : ((gx >= WW) ? (2 * (WW - 1) - gx) : gx);
                        tmp[t] = src[rowbase[k] + gx];
                    }
                    pre[k] = make_float4(tmp[0], tmp[1], tmp[2], tmp[3]);
                }
            }
        }
    };

    // ---- per-thread vert geometry: 32 cols x 4 groups x 8 rows ----
    const int tx  = tid & 31;
    const int ty0 = (tid >> 5) << 3;        // 0,8,16,24
    const int x   = x0 + tx;
    int px = x - PAD;  px = (px < 0) ? -px : px;       // x-10 <= 501, no upper reflect
    const int a_base = (y0 + ty0) * WW + x;            // a = noisy[y][x], coalesced
    int p_off[8];
    #pragma unroll
    for (int i = 0; i < 8; ++i) {
        int py = y0 + ty0 + i - PAD;
        py = (py < 0) ? -py : py;                      // py <= 501, no upper reflect
        p_off[i] = py * WW + px;                       // p = noisy[refl(y-10)][refl(x-10)]
    }

    // hsum geometry: 104 units = 52 rows x 2 segments of 16 cols
    const int hrow = tid >> 1;
    const int hseg = (tid & 1) << 4;        // 0 or 16

    float num[8], den[8];
    #pragma unroll
    for (int i = 0; i < 8; ++i) { num[i] = 0.f; den[i] = 0.f; }

    prefetch(0);

    for (int b = 0; b < B; ++b) {
        const float* src = noisy + (size_t)(b * CCH + ch) * (HH * WW);
        __syncthreads();                    // previous tile/hs fully consumed
        #pragma unroll
        for (int k = 0; k < NPRE; ++k)
            if (valid[k]) *(float4*)ldsp[k] = pre[k];
        __syncthreads();

        if (b < B - 1) prefetch(b + 1);     // latency hides behind hsum+vert

        // a/p for this batch: coalesced global b32, lines are L1/L2-warm
        float av[8], pv[8];
        #pragma unroll
        for (int i = 0; i < 8; ++i) {
            av[i] = src[a_base + i * WW];
            pv[i] = src[p_off[i]];
        }

        // ---- horizontal box sums: 36 floats -> 16 outputs per unit ----
        if (tid < PTY * 2) {
            float v[36];
            #pragma unroll
            for (int q = 0; q < 9; ++q)
                *(float4*)&v[q * 4] = *(const float4*)&tile[hrow][hseg + (q << 2)];
            float s1 = 0.f, s2 = 0.f;
            #pragma unroll
            for (int k = 0; k <= 20; ++k) { s1 += v[k]; s2 = fmaf(v[k], v[k], s2); }
            hs_t[hseg][hrow] = make_float2(s1, s2);
            #pragma unroll
            for (int j = 1; j < 16; ++j) {
                float vo = v[j - 1], vn = v[j + 20];
                s1 += vn - vo;
                s2 += vn * vn - vo * vo;
                hs_t[hseg + j][hrow] = make_float2(s1, s2);
            }
        }
        __syncthreads();

        // ---- vertical: 8 rows/thread, 21-row history in registers ----
        float2 hh[21];
        #pragma unroll
        for (int k = 0; k < 21; ++k) hh[k] = hs_t[tx][ty0 + k];
        float vs1 = 0.f, vs2 = 0.f;
        #pragma unroll
        for (int k = 0; k < 21; ++k) { vs1 += hh[k].x; vs2 += hh[k].y; }

        const float kE = (-100.0f / 441.0f) * 1.44269504088896f;  // 1/h^2*1/n*1/ln2
        {
            float a = av[0];
            float dd = fmaf(a, fmaf(441.f, a, -2.f * vs1), vs2);
            float w = exp2f(dd * kE);
            num[0] += w * pv[0]; den[0] += w;
        }
        #pragma unroll
        for (int i = 1; i < 8; ++i) {
            float2 hn = hs_t[tx][ty0 + 20 + i];
            vs1 += hn.x - hh[i - 1].x;
            vs2 += hn.y - hh[i - 1].y;
            float a = av[i];
            float dd = fmaf(a, fmaf(441.f, a, -2.f * vs1), vs2);
            float w = exp2f(dd * kE);
            num[i] += w * pv[i]; den[i] += w;
        }
    }

    // ---- epilogue: identical value for all 8 batch slices ----
    #pragma unroll
    for (int i = 0; i < 8; ++i) {
        int y = y0 + ty0 + i;
        float v = num[i] / (den[i] + 1e-10f);
        v = v < 0.f ? 0.f : (v > 1.f ? 1.f : v);
        #pragma unroll
        for (int b = 0; b < B; ++b)
            out[((size_t)(b * CCH + ch) * HH + y) * WW + x] = v;
    }
}

extern "C" void kernel_launch(void* const* d_in, const int* in_sizes, int n_in,
                              void* d_out, int out_size, void* d_ws, size_t ws_size,
                              hipStream_t stream) {
    const float* noisy = (const float*)d_in[0];
    float* out = (float*)d_out;
    dim3 grid(WW / TSX, HH / TSY, CCH);
    nlm_fused_kernel<<<grid, dim3(NT), 0, stream>>>(noisy, out);
}